// Round 9
// baseline (226.074 us; speedup 1.0000x reference)
//
#include <hip/hip_runtime.h>
#include <hip/hip_bf16.h>

typedef unsigned int u32;
typedef unsigned short ushort_t;
typedef __bf16 bf16x8 __attribute__((ext_vector_type(8)));
typedef float f32x4 __attribute__((ext_vector_type(4)));
typedef unsigned short ushort8 __attribute__((ext_vector_type(8)));

// Problem constants
#define GM 25088          // B*T*14*14
#define GK 768            // CIN*P*P
#define GN 768            // D

__device__ __forceinline__ ushort_t f2bf(float f) {
    __bf16 h = (__bf16)f;                       // hw v_cvt (RNE) on gfx950
    return __builtin_bit_cast(ushort_t, h);
}

__device__ __forceinline__ float bf2f(ushort_t u) {
    return __uint_as_float(((u32)u) << 16);
}

__device__ __forceinline__ ushort8 cvt8(f32x4 f0, f32x4 f1) {
    ushort8 r;
    r[0] = f2bf(f0[0]); r[1] = f2bf(f0[1]); r[2] = f2bf(f0[2]); r[3] = f2bf(f0[3]);
    r[4] = f2bf(f1[0]); r[5] = f2bf(f1[1]); r[6] = f2bf(f1[2]); r[7] = f2bf(f1[3]);
    return r;
}

__device__ __forceinline__ void load_lds16(const void* g, void* l) {
    __builtin_amdgcn_global_load_lds(
        (const __attribute__((address_space(1))) u32*)g,
        (__attribute__((address_space(3))) u32*)l, 16, 0, 0);
}

// ---------------------------------------------------------------
// pack: blocks [0,1792) = pack_a (LDS-transpose per (b,t,h) band);
//       blocks [1792,1828) = pack_w. Both XOR-swizzled for gemm.
// ---------------------------------------------------------------
__global__ __launch_bounds__(256) void pack(const float* __restrict__ x,
                                            const float* __restrict__ projw,
                                            ushort_t* __restrict__ Ap,
                                            ushort_t* __restrict__ Wp) {
    __shared__ ushort_t Lsm[3 * 16 * 232];   // 22272 B
    int bid = blockIdx.x;
    int tid = threadIdx.x;
    if (bid < 1792) {
        int h = bid % 14;
        int t = (bid / 14) % 8;
        int b = bid / 112;
        for (int chunk = tid; chunk < 1344; chunk += 256) {
            int c = chunk / 448;
            int cc = chunk % 448;
            int p = cc / 28;
            int col0 = (cc % 28) * 8;
            const float* s = x + ((size_t)((b * 3 + c) * 8 + t) * 224 + h * 16 + p) * 224 + col0;
            f32x4 f0 = *(const f32x4*)s;
            f32x4 f1 = *(const f32x4*)(s + 4);
            *(ushort8*)&Lsm[(c * 16 + p) * 232 + col0] = cvt8(f0, f1);
        }
        __syncthreads();
        int mbase = ((b * 8 + t) * 14 + h) * 14;
        for (int chunk = tid; chunk < 1344; chunk += 256) {
            int w = chunk / 96;
            int kc = chunk % 96;
            int k0 = kc * 8;
            int c = k0 >> 8;
            int p = (k0 >> 4) & 15;
            int q0 = k0 & 15;
            ushort8 r = *(const ushort8*)&Lsm[(c * 16 + p) * 232 + w * 16 + q0];
            int mm = mbase + w;
            int bytesw = (kc * 16) ^ ((mm & 7) << 4);
            *(ushort8*)(Ap + (size_t)mm * 768 + (bytesw >> 1)) = r;
        }
    } else {
        int g = (bid - 1792) * 256 + tid;   // [0, 9216)
        int n = g / 12;
        int piece = g % 12;
        const float* src = projw + (size_t)n * 768 + piece * 64;
        int xo = (n & 7) << 4;
        ushort_t* dst = Wp + (size_t)n * 768 + piece * 64;
        #pragma unroll
        for (int i = 0; i < 4; ++i) {
            const float* s = src + i * 16;
            f32x4 f0 = *(const f32x4*)(s);
            f32x4 f1 = *(const f32x4*)(s + 4);
            f32x4 f2 = *(const f32x4*)(s + 8);
            f32x4 f3 = *(const f32x4*)(s + 12);
            int b0 = (i * 32) ^ xo;
            int b1 = (i * 32 + 16) ^ xo;
            *(ushort8*)(dst + (b0 >> 1)) = cvt8(f0, f1);
            *(ushort8*)(dst + (b1 >> 1)) = cvt8(f2, f3);
        }
    }
}

// ---------------------------------------------------------------
// box_mlp: one block per (b,t,dchunk); 16-wide load batching in j
// ---------------------------------------------------------------
__global__ __launch_bounds__(256) void box_mlp(const float* __restrict__ meta,
                                               const float* __restrict__ w1,
                                               const float* __restrict__ w2,
                                               const float* __restrict__ cats,
                                               float* __restrict__ emb) {
    __shared__ float H[3][384];
    int bt = blockIdx.x / 3;
    int dc = blockIdx.x % 3;
    int b = bt / 8, t = bt % 8;
    int tid = threadIdx.x;
    for (int idx = tid; idx < 3 * 384; idx += 256) {
        int o = idx / 384, j = idx % 384;
        const float* mp = meta + ((b * 3 + o) * 8 + t) * 4;
        float s = 0.f;
        #pragma unroll
        for (int i = 0; i < 4; ++i) s += (mp[i] * (1.0f / 224.0f)) * w1[i * 384 + j];
        H[o][j] = fmaxf(s, 0.f);
    }
    __syncthreads();
    int d = dc * 256 + tid;
    const float* wp = w2 + d;
    float acc0 = 0.f, acc1 = 0.f, acc2 = 0.f;
    #pragma unroll 1
    for (int j0 = 0; j0 < 384; j0 += 16) {
        float wv[16];
        #pragma unroll
        for (int u = 0; u < 16; ++u) wv[u] = wp[(size_t)(j0 + u) * 768];
        #pragma unroll
        for (int u = 0; u < 16; ++u) {
            acc0 += H[0][j0 + u] * wv[u];
            acc1 += H[1][j0 + u] * wv[u];
            acc2 += H[2][j0 + u] * wv[u];
        }
    }
    float a[3] = {acc0, acc1, acc2};
    #pragma unroll
    for (int o = 0; o < 3; ++o) {
        emb[((size_t)bt * 3 + o) * 768 + d] =
            fmaxf(a[o], 0.f) + cats[(t * 3 + o) * 768 + d];
    }
}

// ---------------------------------------------------------------
// GEMM: Cb[m][n] = bf16( sum_k A[m][k]*Bt[n][k] + pb[n] )
// 128x128 tile, BK=64, 4 waves (2x2), single-buffer 32KB LDS,
// pre-swizzled operands (0 bank conflicts), XCD-chunked.
// ---------------------------------------------------------------
__global__ __launch_bounds__(256) void gemm_bt(const ushort_t* __restrict__ A,
                                               const ushort_t* __restrict__ Bt,
                                               const float* __restrict__ pb,
                                               ushort_t* __restrict__ Cb) {
    __shared__ ushort_t lA[128 * 64];
    __shared__ ushort_t lB[128 * 64];
    int tid = threadIdx.x;
    int bid = blockIdx.x;
    int wid = (bid & 7) * 147 + (bid >> 3);
    int bm = wid / 6;
    int bn = wid % 6;
    size_t m0 = (size_t)bm * 128, n0 = (size_t)bn * 128;
    int w = tid >> 6, lane = tid & 63;
    int wr = w >> 1, wc = w & 1;
    int r15 = lane & 15;
    int xoU = (lane & 7) << 3;          // swizzle XOR in ushort units

    f32x4 acc[4][4] = {};

    for (int kt = 0; kt < 12; ++kt) {
        int k0 = kt * 64;
        __syncthreads();
        #pragma unroll
        for (int r = 0; r < 4; ++r) {
            int cidx = r * 256 + tid;
            int row = cidx >> 3;
            int col = (cidx & 7) * 8;
            load_lds16(A + ((m0 + row) * 768 + k0 + col), &lA[(size_t)cidx * 8]);
        }
        #pragma unroll
        for (int r = 0; r < 4; ++r) {
            int cidx = r * 256 + tid;
            int row = cidx >> 3;
            int col = (cidx & 7) * 8;
            load_lds16(Bt + ((n0 + row) * 768 + k0 + col), &lB[(size_t)cidx * 8]);
        }
        __syncthreads();
        #pragma unroll
        for (int kk = 0; kk < 2; ++kk) {
            int cs = (kk * 32 + (lane >> 4) * 8) ^ xoU;
            bf16x8 af[4], bfr[4];
            #pragma unroll
            for (int mi = 0; mi < 4; ++mi)
                af[mi] = *(const bf16x8*)&lA[(wr * 64 + mi * 16 + r15) * 64 + cs];
            #pragma unroll
            for (int ni = 0; ni < 4; ++ni)
                bfr[ni] = *(const bf16x8*)&lB[(wc * 64 + ni * 16 + r15) * 64 + cs];
            #pragma unroll
            for (int mi = 0; mi < 4; ++mi)
                #pragma unroll
                for (int ni = 0; ni < 4; ++ni)
                    acc[mi][ni] = __builtin_amdgcn_mfma_f32_16x16x32_bf16(
                        af[mi], bfr[ni], acc[mi][ni], 0, 0, 0);
        }
    }

    int rbase = (lane >> 4) * 4;
    #pragma unroll
    for (int ni = 0; ni < 4; ++ni) {
        size_t col = n0 + wc * 64 + ni * 16 + r15;
        float pbv = pb[col];
        #pragma unroll
        for (int mi = 0; mi < 4; ++mi) {
            size_t row = m0 + wr * 64 + mi * 16 + rbase;
            #pragma unroll
            for (int j = 0; j < 4; ++j) {
                Cb[(row + j) * 768 + col] = f2bf(acc[mi][ni][j] + pbv);
            }
        }
    }
}

// ---------------------------------------------------------------
// ROI bilinear crop + emb add + final layout. feat is bf16.
// 2688 blocks (one (b,t,o,i) each), XCD-chunked. 192 threads =
// 96 d-groups (8 elems, 16B loads) x 2 j-halves.
// ---------------------------------------------------------------
__global__ __launch_bounds__(192) void roi_kernel(const float* __restrict__ meta,
                                                  const ushort_t* __restrict__ featB,
                                                  const float* __restrict__ emb,
                                                  float* __restrict__ out) {
    int bid = blockIdx.x;               // 2688 = 8*336
    int wid = (bid & 7) * 336 + (bid >> 3);
    int i = wid % 7; int r = wid / 7;
    int o = r % 3; r /= 3;
    int t = r % 8;
    int b = r / 8;

    int tid = threadIdx.x;
    int dg = tid % 96;
    int jh = tid / 96;                  // 0 -> j 0..3, 1 -> j 4..6
    int d = dg * 8;

    const float* mp = meta + ((b * 3 + o) * 8 + t) * 4;
    float x1 = mp[0] * (1.f / 16.f);
    float y1 = mp[1] * (1.f / 16.f);
    float x2 = mp[2] * (1.f / 16.f);
    float y2 = mp[3] * (1.f / 16.f);

    float ci = (i + 0.5f) * (1.f / 7.f);
    float yg = y1 + ci * (y2 - y1) - 0.5f;
    float y0f = floorf(yg);
    float wy = yg - y0f;
    int y0 = min(max((int)y0f, 0), 13);
    int y1c = min(y0 + 1, 13);

    int bt = b * 8 + t;
    const ushort_t* fbase = featB + (size_t)bt * 196 * 768;
    const float* ep = emb + ((size_t)bt * 3 + o) * 768;
    f32x4 ev0 = *(const f32x4*)(ep + d);
    f32x4 ev1 = *(const f32x4*)(ep + d + 4);

    float* obase = out + (((size_t)(b * 3 + o) * 8 + t) * 49 + i * 7) * 768 + d;

    int jend = jh ? 7 : 4;
    for (int j = jh * 4; j < jend; ++j) {
        float cj = (j + 0.5f) * (1.f / 7.f);
        float xgv = x1 + cj * (x2 - x1) - 0.5f;
        float x0f = floorf(xgv);
        float wx = xgv - x0f;
        int x0 = min(max((int)x0f, 0), 13);
        int x1i = min(x0 + 1, 13);

        ushort8 u00 = *(const ushort8*)(fbase + ((size_t)y0 * 14 + x0) * 768 + d);
        ushort8 u01 = *(const ushort8*)(fbase + ((size_t)y0 * 14 + x1i) * 768 + d);
        ushort8 u10 = *(const ushort8*)(fbase + ((size_t)y1c * 14 + x0) * 768 + d);
        ushort8 u11 = *(const ushort8*)(fbase + ((size_t)y1c * 14 + x1i) * 768 + d);

        float w00 = (1.f - wy) * (1.f - wx);
        float w01 = (1.f - wy) * wx;
        float w10 = wy * (1.f - wx);
        float w11 = wy * wx;

        f32x4 r0, r1;
        #pragma unroll
        for (int e = 0; e < 4; ++e) {
            r0[e] = bf2f(u00[e]) * w00 + bf2f(u01[e]) * w01
                  + bf2f(u10[e]) * w10 + bf2f(u11[e]) * w11 + ev0[e];
            r1[e] = bf2f(u00[e + 4]) * w00 + bf2f(u01[e + 4]) * w01
                  + bf2f(u10[e + 4]) * w10 + bf2f(u11[e + 4]) * w11 + ev1[e];
        }
        *(f32x4*)(obase + (size_t)j * 768) = r0;
        *(f32x4*)(obase + (size_t)j * 768 + 4) = r1;
    }
}

extern "C" void kernel_launch(void* const* d_in, const int* in_sizes, int n_in,
                              void* d_out, int out_size, void* d_ws, size_t ws_size,
                              hipStream_t stream) {
    const float* x     = (const float*)d_in[0];
    const float* meta  = (const float*)d_in[1];
    const float* projw = (const float*)d_in[2];
    const float* projb = (const float*)d_in[3];
    const float* cats  = (const float*)d_in[4];
    const float* w1    = (const float*)d_in[5];
    const float* w2    = (const float*)d_in[6];
    float* out = (float*)d_out;

    char* ws = (char*)d_ws;
    const size_t szA  = (size_t)GM * GK * 2;         // 38,535,168 (swizzled bf16 A)
    const size_t szW  = (size_t)GN * GK * 2;         //  1,179,648 (swizzled bf16 W)
    const size_t szFB = (size_t)GM * GN * 2;         // 38,535,168 (bf16 feat)
    ushort_t* Ap    = (ushort_t*)(ws);
    ushort_t* Wp    = (ushort_t*)(ws + szA);
    ushort_t* featB = (ushort_t*)(ws + szA + szW);
    float*    emb   = (float*)(ws + szA + szW + szFB);

    pack<<<1828, 256, 0, stream>>>(x, projw, Ap, Wp);
    box_mlp<<<384, 256, 0, stream>>>(meta, w1, w2, cats, emb);
    gemm_bt<<<1176, 256, 0, stream>>>(Ap, Wp, projb, featB);
    roi_kernel<<<2688, 192, 0, stream>>>(meta, featB, emb, out);
}